// Round 5
// baseline (165.227 us; speedup 1.0000x reference)
//
#include <hip/hip_runtime.h>

#define GRID_S 7
#define NUM_CLASSES 80
#define D_DIM 90
#define LAMBDA_COORD 5.0f
#define LAMBDA_NOOBJ 0.5f
#define EPS_IOU 1e-6f
#define EPS_SQRT 1e-6f

// Stream blocks: GA*256 threads multiple of 45 (45 float4 == 2 cells).
// 630*256 = 161280 = 45*3584; 4515840/161280 = 28 iters exactly.
#define GA 630
#define UNROLL 4

__device__ __forceinline__ float iou_img(float cx1, float cy1, float w1, float h1,
                                         float cx2, float cy2, float w2, float h2) {
    float ixmin = fmaxf(cx1 - w1 * 0.5f, cx2 - w2 * 0.5f);
    float iymin = fmaxf(cy1 - h1 * 0.5f, cy2 - h2 * 0.5f);
    float ixmax = fminf(cx1 + w1 * 0.5f, cx2 + w2 * 0.5f);
    float iymax = fminf(cy1 + h1 * 0.5f, cy2 + h2 * 0.5f);
    float iw = fmaxf(ixmax - ixmin, 0.0f);
    float ih = fmaxf(iymax - iymin, 0.0f);
    float inter = iw * ih;
    float uni = w1 * h1 + w2 * h2 - inter;
    return inter / (uni + EPS_IOU);
}

// part layout: per block, 4 floats: [n_obj, coord, conf, cls]
__global__ __launch_bounds__(256, 4) void yolo_main_kernel(
        const float* __restrict__ pred, const float* __restrict__ targ,
        float* __restrict__ part, int ncells) {
    const int tid = threadIdx.x;
    float v_obj = 0.0f, v_coord = 0.0f, v_conf = 0.0f, v_cls = 0.0f;

    if (blockIdx.x < GA) {
        // ================= stream path: class loss =================
        const int NF4 = (ncells * D_DIM) >> 2;
        const int T = GA * 256;                    // 161280
        const int t = blockIdx.x * 256 + tid;
        const int phase = t % 45;
        const int GSTRIDE = T / 45;                // 3584

        float w0[4], w1[4];
        #pragma unroll
        for (int e = 0; e < 4; ++e) {
            int fe = phase * 4 + e;
            int ce = (fe >= 90) ? 1 : 0;
            int de = fe - 90 * ce;
            float cw = (de >= 10) ? 1.0f : 0.0f;
            w0[e] = ce ? 0.0f : cw;
            w1[e] = ce ? cw : 0.0f;
        }

        const float4* p4 = (const float4*)pred;
        const float4* t4 = (const float4*)targ;
        float acc = 0.0f;

        const int nfull = NF4 / T;                 // 28 for the bench shape
        const int nquad = nfull / UNROLL;          // 7
        int j = t;
        int g = t / 45;

        for (int q = 0; q < nquad; ++q) {
            float4 P[UNROLL], Tv[UNROLL];
            float O0[UNROLL], O1[UNROLL];
            #pragma unroll
            for (int u = 0; u < UNROLL; ++u) {
                const int ju = j + u * T;
                P[u] = p4[ju];
                Tv[u] = t4[ju];
                const float* ob = targ + (size_t)(g + u * GSTRIDE) * 180;
                O0[u] = ob[4];
                O1[u] = ob[94];
            }
            #pragma unroll
            for (int u = 0; u < UNROLL; ++u) {
                float f0 = (O0[u] == 1.0f) ? 1.0f : 0.0f;
                float f1 = (O1[u] == 1.0f) ? 1.0f : 0.0f;
                float d0 = P[u].x - Tv[u].x;
                float d1 = P[u].y - Tv[u].y;
                float d2 = P[u].z - Tv[u].z;
                float d3 = P[u].w - Tv[u].w;
                acc = fmaf(d0 * d0, fmaf(w1[0], f1, w0[0] * f0), acc);
                acc = fmaf(d1 * d1, fmaf(w1[1], f1, w0[1] * f0), acc);
                acc = fmaf(d2 * d2, fmaf(w1[2], f1, w0[2] * f0), acc);
                acc = fmaf(d3 * d3, fmaf(w1[3], f1, w0[3] * f0), acc);
            }
            j += UNROLL * T;
            g += UNROLL * GSTRIDE;
        }
        // generic remainder (empty for the bench shape)
        for (int r = nquad * UNROLL; r < nfull; ++r) {
            float4 p = p4[j];
            float4 tv = t4[j];
            const float* ob = targ + (size_t)g * 180;
            float f0 = (ob[4] == 1.0f) ? 1.0f : 0.0f;
            float f1 = (ob[94] == 1.0f) ? 1.0f : 0.0f;
            float d0 = p.x - tv.x, d1 = p.y - tv.y, d2 = p.z - tv.z, d3 = p.w - tv.w;
            acc = fmaf(d0 * d0, fmaf(w1[0], f1, w0[0] * f0), acc);
            acc = fmaf(d1 * d1, fmaf(w1[1], f1, w0[1] * f0), acc);
            acc = fmaf(d2 * d2, fmaf(w1[2], f1, w0[2] * f0), acc);
            acc = fmaf(d3 * d3, fmaf(w1[3], f1, w0[3] * f0), acc);
            j += T; g += GSTRIDE;
        }
        if (j < NF4) {
            float4 p = p4[j];
            float4 tv = t4[j];
            const float* ob = targ + (size_t)g * 180;
            float f0 = (ob[4] == 1.0f) ? 1.0f : 0.0f;
            float f1 = (ob[94] == 1.0f) ? 1.0f : 0.0f;
            float d0 = p.x - tv.x, d1 = p.y - tv.y, d2 = p.z - tv.z, d3 = p.w - tv.w;
            acc = fmaf(d0 * d0, fmaf(w1[0], f1, w0[0] * f0), acc);
            acc = fmaf(d1 * d1, fmaf(w1[1], f1, w0[1] * f0), acc);
            acc = fmaf(d2 * d2, fmaf(w1[2], f1, w0[2] * f0), acc);
            acc = fmaf(d3 * d3, fmaf(w1[3], f1, w0[3] * f0), acc);
        }
        v_cls = acc * (1.0f / (float)NUM_CLASSES);
    } else {
        // ================= gather path: box / conf / n_obj =================
        const int cell = (blockIdx.x - GA) * 256 + tid;
        if (cell < ncells) {
            const float2* cp2 = (const float2*)(pred + (size_t)cell * D_DIM);
            const float2* ct2 = (const float2*)(targ + (size_t)cell * D_DIM);
            float2 pA = cp2[0], pB = cp2[1], pC = cp2[2], pD = cp2[3], pE = cp2[4];
            float2 tA = ct2[0], tB = ct2[1], tC = ct2[2];

            float b1x = pA.x, b1y = pA.y, b1w = pB.x, b1h = pB.y, b1c = pC.x;
            float b2x = pC.y, b2y = pD.x, b2w = pD.y, b2h = pE.x, b2c = pE.y;
            float tbx = tA.x, tby = tA.y, tbw = tB.x, tbh = tB.y;
            float tobj = tC.x;

            const int gxy = cell % (GRID_S * GRID_S);
            const float gy = (float)(gxy / GRID_S);
            const float gx = (float)(gxy % GRID_S);
            const float invS = 1.0f / (float)GRID_S;
            float c1x = (gx + b1x) * invS, c1y = (gy + b1y) * invS;
            float c2x = (gx + b2x) * invS, c2y = (gy + b2y) * invS;
            float ctx = (gx + tbx) * invS, cty = (gy + tby) * invS;

            float iou1 = iou_img(c1x, c1y, b1w, b1h, ctx, cty, tbw, tbh);
            float iou2 = iou_img(c2x, c2y, b2w, b2h, ctx, cty, tbw, tbh);
            bool resp1 = iou1 > iou2;

            float bx = resp1 ? b1x : b2x;
            float by = resp1 ? b1y : b2y;
            float bw = resp1 ? b1w : b2w;
            float bh = resp1 ? b1h : b2h;
            float bc = resp1 ? b1c : b2c;

            bool obj = (tobj == 1.0f);
            float objf = obj ? 1.0f : 0.0f;

            float ddx = bx - tbx, ddy = by - tby;
            float dxy2 = ddx * ddx + ddy * ddy;
            float swpw = sqrtf(fmaxf(bw, EPS_SQRT));
            float swph = sqrtf(fmaxf(bh, EPS_SQRT));
            float swtw = sqrtf(fmaxf(tbw, EPS_SQRT));
            float swth = sqrtf(fmaxf(tbh, EPS_SQRT));
            float dw = swpw - swtw, dh = swph - swth;
            float dwh2 = dw * dw + dh * dh;
            float coord = 0.5f * dxy2 + 0.5f * dwh2;

            float dco = bc - 1.0f;
            float conf_obj = dco * dco;
            float conf_noobj = LAMBDA_NOOBJ * (b1c * b1c + b2c * b2c);

            v_obj = objf;
            v_coord = coord * objf;
            v_conf = obj ? conf_obj : conf_noobj;
        }
    }

    // ---- block reduction (both paths) ----
    #pragma unroll
    for (int off = 32; off > 0; off >>= 1) {
        v_obj   += __shfl_down(v_obj, off, 64);
        v_coord += __shfl_down(v_coord, off, 64);
        v_conf  += __shfl_down(v_conf, off, 64);
        v_cls   += __shfl_down(v_cls, off, 64);
    }
    __shared__ float red[4][4];
    const int lane = tid & 63;
    const int wid = tid >> 6;
    if (lane == 0) {
        red[wid][0] = v_obj;
        red[wid][1] = v_coord;
        red[wid][2] = v_conf;
        red[wid][3] = v_cls;
    }
    __syncthreads();
    if (tid < 4) {
        float s = red[0][tid] + red[1][tid] + red[2][tid] + red[3][tid];
        part[(size_t)blockIdx.x * 4 + tid] = s;
    }
}

__global__ __launch_bounds__(1024) void yolo_final_kernel(
        const float* __restrict__ part, float* __restrict__ out,
        int nblocks, int ncells) {
    const int tid = threadIdx.x;
    float a0 = 0.0f, a1 = 0.0f, a2 = 0.0f, a3 = 0.0f;
    const float4* p4 = (const float4*)part;
    for (int b = tid; b < nblocks; b += 1024) {
        float4 v = p4[b];
        a0 += v.x; a1 += v.y; a2 += v.z; a3 += v.w;
    }
    #pragma unroll
    for (int off = 32; off > 0; off >>= 1) {
        a0 += __shfl_down(a0, off, 64);
        a1 += __shfl_down(a1, off, 64);
        a2 += __shfl_down(a2, off, 64);
        a3 += __shfl_down(a3, off, 64);
    }
    __shared__ float red[16][4];
    const int wid = tid >> 6;
    if ((tid & 63) == 0) {
        red[wid][0] = a0; red[wid][1] = a1; red[wid][2] = a2; red[wid][3] = a3;
    }
    __syncthreads();
    if (tid == 0) {
        float n_obj = 0.0f, coord = 0.0f, conf = 0.0f, cls = 0.0f;
        #pragma unroll
        for (int w = 0; w < 16; ++w) {
            n_obj += red[w][0]; coord += red[w][1];
            conf  += red[w][2]; cls   += red[w][3];
        }
        float n_cells = (float)ncells;
        float conf_count = n_obj + 2.0f * (n_cells - n_obj);
        float denom = fmaxf(n_obj, 1.0f);
        out[0] = LAMBDA_COORD * coord / denom + conf / fmaxf(conf_count, 1.0f) + cls / denom;
    }
}

extern "C" void kernel_launch(void* const* d_in, const int* in_sizes, int n_in,
                              void* d_out, int out_size, void* d_ws, size_t ws_size,
                              hipStream_t stream) {
    const float* pred = (const float*)d_in[0];
    const float* targ = (const float*)d_in[1];
    float* part = (float*)d_ws;
    float* out = (float*)d_out;

    const int ncells = in_sizes[0] / D_DIM;          // B * S * S (even)
    const int GB = (ncells + 255) / 256;             // gather blocks
    const int nblocks = GA + GB;

    yolo_main_kernel<<<nblocks, 256, 0, stream>>>(pred, targ, part, ncells);
    yolo_final_kernel<<<1, 1024, 0, stream>>>(part, out, nblocks, ncells);
}

// Round 6
// 159.853 us; speedup vs baseline: 1.0336x; 1.0336x over previous
//
#include <hip/hip_runtime.h>

#define GRID_S 7
#define NUM_CLASSES 80
#define D_DIM 90
#define LAMBDA_COORD 5.0f
#define LAMBDA_NOOBJ 0.5f
#define EPS_IOU 1e-6f
#define EPS_SQRT 1e-6f

// Stream structure: a "group" = 2 cells = 180 floats = 45 float4.
// Each block-iteration processes one window of 225 float4 = 5 whole groups,
// so every group's flag/box elements are held by threads of the same block
// in the same iteration -> LDS exchange, zero extra VMEM instructions.
#define SB 1024          // stream blocks (= 4 per CU, all resident)
#define WIN 225          // float4 per window
#define GPW 5            // groups per window

__device__ __forceinline__ float iou_img(float cx1, float cy1, float w1, float h1,
                                         float cx2, float cy2, float w2, float h2) {
    float ixmin = fmaxf(cx1 - w1 * 0.5f, cx2 - w2 * 0.5f);
    float iymin = fmaxf(cy1 - h1 * 0.5f, cy2 - h2 * 0.5f);
    float ixmax = fminf(cx1 + w1 * 0.5f, cx2 + w2 * 0.5f);
    float iymax = fminf(cy1 + h1 * 0.5f, cy2 + h2 * 0.5f);
    float iw = fmaxf(ixmax - ixmin, 0.0f);
    float ih = fmaxf(iymax - iymin, 0.0f);
    float inter = iw * ih;
    float uni = w1 * h1 + w2 * h2 - inter;
    return inter / (uni + EPS_IOU);
}

// part layout: per block, 4 floats: [n_obj, coord, conf, cls]
__global__ __launch_bounds__(256, 4) void yolo_fused_kernel(
        const float* __restrict__ pred, const float* __restrict__ targ,
        float* __restrict__ part, int ncells) {
    const int tid = threadIdx.x;
    const int G2 = ncells >> 1;                    // 2-cell groups (ncells even)
    const int nwin = (G2 + GPW - 1) / GPW;
    const int iters = (nwin + SB - 1) / SB;

    const bool is_stream = tid < WIN;
    const int q = tid % 45;                        // float4 index within group
    const int lg = tid / 45;                       // local group (0..4 for stream)

    // per-element class weights: element e of this thread's float4 is global
    // float index fe = q*4+e within the 180-float group; cell = fe>=90;
    // it is a class element iff (fe mod 90) >= 10.
    float w0[4], w1[4];
    #pragma unroll
    for (int e = 0; e < 4; ++e) {
        int fe = q * 4 + e;
        int ce = (fe >= 90) ? 1 : 0;
        int de = fe - 90 * ce;
        float cw = (de >= 10) ? 1.0f : 0.0f;
        w0[e] = ce ? 0.0f : cw;
        w1[e] = ce ? cw : 0.0f;
    }

    // Staged per group: pbox[0..9]=pred fe0..9 (cell0 boxes), [10..19]=fe90..99
    //                   tbox[0..4]=targ fe0..4 (cell0 box+flag), [5..9]=fe90..94
    __shared__ float pbox[2][GPW][20];
    __shared__ float tbox[2][GPW][10];

    // box-loss threads: 10 spare threads in wave 3 (lanes 40..49)
    const bool is_box = (tid >= 232) && (tid < 232 + 2 * GPW);
    const int bgid = tid - 232;                    // 0..9
    const int blg = bgid >> 1;                     // group 0..4
    const int bcell = bgid & 1;                    // cell within group

    const float4* p4 = (const float4*)pred;
    const float4* t4 = (const float4*)targ;

    float acc = 0.0f, v_obj = 0.0f, v_coord = 0.0f, v_conf = 0.0f;

    for (int i = 0; i < iters; ++i) {
        const int win = i * SB + blockIdx.x;
        const int gbase = win * GPW;
        const int p = i & 1;
        const int g = gbase + lg;
        const bool v = is_stream && (g < G2);
        float4 P, Tv;
        if (v) {
            const int j = win * WIN + tid;         // float4 index (contiguous per wave)
            P = p4[j];
            Tv = t4[j];
            // stage box/flag elements for this group
            if (q == 0) {
                pbox[p][lg][0] = P.x; pbox[p][lg][1] = P.y;
                pbox[p][lg][2] = P.z; pbox[p][lg][3] = P.w;
                tbox[p][lg][0] = Tv.x; tbox[p][lg][1] = Tv.y;
                tbox[p][lg][2] = Tv.z; tbox[p][lg][3] = Tv.w;
            } else if (q == 1) {
                pbox[p][lg][4] = P.x; pbox[p][lg][5] = P.y;
                pbox[p][lg][6] = P.z; pbox[p][lg][7] = P.w;
                tbox[p][lg][4] = Tv.x;             // cell0 obj flag (fe 4)
            } else if (q == 2) {
                pbox[p][lg][8] = P.x; pbox[p][lg][9] = P.y;
            } else if (q == 22) {                  // fe 88..91
                pbox[p][lg][10] = P.z; pbox[p][lg][11] = P.w;
                tbox[p][lg][5] = Tv.z; tbox[p][lg][6] = Tv.w;
            } else if (q == 23) {                  // fe 92..95
                pbox[p][lg][12] = P.x; pbox[p][lg][13] = P.y;
                pbox[p][lg][14] = P.z; pbox[p][lg][15] = P.w;
                tbox[p][lg][7] = Tv.x; tbox[p][lg][8] = Tv.y;
                tbox[p][lg][9] = Tv.z;             // cell1 obj flag (fe 94)
            } else if (q == 24) {                  // fe 96..99
                pbox[p][lg][16] = P.x; pbox[p][lg][17] = P.y;
                pbox[p][lg][18] = P.z; pbox[p][lg][19] = P.w;
            }
        }
        __syncthreads();
        if (v) {
            float f0 = (tbox[p][lg][4] == 1.0f) ? 1.0f : 0.0f;
            float f1 = (tbox[p][lg][9] == 1.0f) ? 1.0f : 0.0f;
            float d0 = P.x - Tv.x, d1 = P.y - Tv.y;
            float d2 = P.z - Tv.z, d3 = P.w - Tv.w;
            acc = fmaf(d0 * d0, fmaf(w1[0], f1, w0[0] * f0), acc);
            acc = fmaf(d1 * d1, fmaf(w1[1], f1, w0[1] * f0), acc);
            acc = fmaf(d2 * d2, fmaf(w1[2], f1, w0[2] * f0), acc);
            acc = fmaf(d3 * d3, fmaf(w1[3], f1, w0[3] * f0), acc);
        }
        if (is_box) {
            const int bg = gbase + blg;
            if (bg < G2) {
                const float* pb = &pbox[p][blg][bcell * 10];
                const float* tb = &tbox[p][blg][bcell * 5];
                float b1x = pb[0], b1y = pb[1], b1w = pb[2], b1h = pb[3], b1c = pb[4];
                float b2x = pb[5], b2y = pb[6], b2w = pb[7], b2h = pb[8], b2c = pb[9];
                float tbx = tb[0], tby = tb[1], tbw = tb[2], tbh = tb[3];
                float tobj = tb[4];

                const int cell = 2 * bg + bcell;
                const int gxy = cell % (GRID_S * GRID_S);
                const float gy = (float)(gxy / GRID_S);
                const float gx = (float)(gxy % GRID_S);
                const float invS = 1.0f / (float)GRID_S;
                float c1x = (gx + b1x) * invS, c1y = (gy + b1y) * invS;
                float c2x = (gx + b2x) * invS, c2y = (gy + b2y) * invS;
                float ctx = (gx + tbx) * invS, cty = (gy + tby) * invS;

                float iou1 = iou_img(c1x, c1y, b1w, b1h, ctx, cty, tbw, tbh);
                float iou2 = iou_img(c2x, c2y, b2w, b2h, ctx, cty, tbw, tbh);
                bool resp1 = iou1 > iou2;

                float bx = resp1 ? b1x : b2x;
                float by = resp1 ? b1y : b2y;
                float bw = resp1 ? b1w : b2w;
                float bh = resp1 ? b1h : b2h;
                float bc = resp1 ? b1c : b2c;

                bool obj = (tobj == 1.0f);
                float objf = obj ? 1.0f : 0.0f;

                float ddx = bx - tbx, ddy = by - tby;
                float dxy2 = ddx * ddx + ddy * ddy;
                float swpw = sqrtf(fmaxf(bw, EPS_SQRT));
                float swph = sqrtf(fmaxf(bh, EPS_SQRT));
                float swtw = sqrtf(fmaxf(tbw, EPS_SQRT));
                float swth = sqrtf(fmaxf(tbh, EPS_SQRT));
                float dw = swpw - swtw, dh = swph - swth;
                float dwh2 = dw * dw + dh * dh;
                float coord = 0.5f * dxy2 + 0.5f * dwh2;

                float dco = bc - 1.0f;
                float conf_obj = dco * dco;
                float conf_noobj = LAMBDA_NOOBJ * (b1c * b1c + b2c * b2c);

                v_obj += objf;
                v_coord += coord * objf;
                v_conf += obj ? conf_obj : conf_noobj;
            }
        }
    }

    float v_cls = acc * (1.0f / (float)NUM_CLASSES);

    // ---- block reduction ----
    #pragma unroll
    for (int off = 32; off > 0; off >>= 1) {
        v_obj   += __shfl_down(v_obj, off, 64);
        v_coord += __shfl_down(v_coord, off, 64);
        v_conf  += __shfl_down(v_conf, off, 64);
        v_cls   += __shfl_down(v_cls, off, 64);
    }
    __shared__ float red[4][4];
    const int lane = tid & 63;
    const int wid = tid >> 6;
    if (lane == 0) {
        red[wid][0] = v_obj;
        red[wid][1] = v_coord;
        red[wid][2] = v_conf;
        red[wid][3] = v_cls;
    }
    __syncthreads();
    if (tid < 4) {
        float s = red[0][tid] + red[1][tid] + red[2][tid] + red[3][tid];
        part[(size_t)blockIdx.x * 4 + tid] = s;
    }
}

__global__ __launch_bounds__(1024) void yolo_final_kernel(
        const float* __restrict__ part, float* __restrict__ out,
        const float* __restrict__ pred, const float* __restrict__ targ,
        int nblocks, int ncells) {
    const int tid = threadIdx.x;
    float a0 = 0.0f, a1 = 0.0f, a2 = 0.0f, a3 = 0.0f;
    const float4* p4 = (const float4*)part;
    for (int b = tid; b < nblocks; b += 1024) {
        float4 v = p4[b];
        a0 += v.x; a1 += v.y; a2 += v.z; a3 += v.w;
    }
    #pragma unroll
    for (int off = 32; off > 0; off >>= 1) {
        a0 += __shfl_down(a0, off, 64);
        a1 += __shfl_down(a1, off, 64);
        a2 += __shfl_down(a2, off, 64);
        a3 += __shfl_down(a3, off, 64);
    }
    __shared__ float red[16][4];
    const int wid = tid >> 6;
    if ((tid & 63) == 0) {
        red[wid][0] = a0; red[wid][1] = a1; red[wid][2] = a2; red[wid][3] = a3;
    }
    __syncthreads();
    if (tid == 0) {
        float n_obj = 0.0f, coord = 0.0f, conf = 0.0f, cls = 0.0f;
        #pragma unroll
        for (int w = 0; w < 16; ++w) {
            n_obj += red[w][0]; coord += red[w][1];
            conf  += red[w][2]; cls   += red[w][3];
        }
        // odd-ncells safety: the stream covers 2*(ncells/2) cells; handle leftover
        if (ncells & 1) {
            const int cell = ncells - 1;
            const float* cp = pred + (size_t)cell * D_DIM;
            const float* ct = targ + (size_t)cell * D_DIM;
            float objf = (ct[4] == 1.0f) ? 1.0f : 0.0f;
            float c = 0.0f;
            for (int k = 10; k < 90; ++k) { float d = cp[k] - ct[k]; c += d * d; }
            cls += c * (1.0f / (float)NUM_CLASSES) * objf;
            const int gxy = cell % (GRID_S * GRID_S);
            const float gy = (float)(gxy / GRID_S);
            const float gx = (float)(gxy % GRID_S);
            const float invS = 1.0f / (float)GRID_S;
            float c1x = (gx + cp[0]) * invS, c1y = (gy + cp[1]) * invS;
            float c2x = (gx + cp[5]) * invS, c2y = (gy + cp[6]) * invS;
            float ctx = (gx + ct[0]) * invS, cty = (gy + ct[1]) * invS;
            float iou1 = iou_img(c1x, c1y, cp[2], cp[3], ctx, cty, ct[2], ct[3]);
            float iou2 = iou_img(c2x, c2y, cp[7], cp[8], ctx, cty, ct[2], ct[3]);
            bool r1 = iou1 > iou2;
            float bx = r1 ? cp[0] : cp[5], by = r1 ? cp[1] : cp[6];
            float bw = r1 ? cp[2] : cp[7], bh = r1 ? cp[3] : cp[8];
            float bc = r1 ? cp[4] : cp[9];
            float ddx = bx - ct[0], ddy = by - ct[1];
            float dw = sqrtf(fmaxf(bw, EPS_SQRT)) - sqrtf(fmaxf(ct[2], EPS_SQRT));
            float dh = sqrtf(fmaxf(bh, EPS_SQRT)) - sqrtf(fmaxf(ct[3], EPS_SQRT));
            float coord1 = 0.5f * (ddx * ddx + ddy * ddy) + 0.5f * (dw * dw + dh * dh);
            float dco = bc - 1.0f;
            n_obj += objf;
            coord += coord1 * objf;
            conf  += (objf == 1.0f) ? dco * dco
                                    : LAMBDA_NOOBJ * (cp[4] * cp[4] + cp[9] * cp[9]);
        }
        float n_cells = (float)ncells;
        float conf_count = n_obj + 2.0f * (n_cells - n_obj);
        float denom = fmaxf(n_obj, 1.0f);
        out[0] = LAMBDA_COORD * coord / denom + conf / fmaxf(conf_count, 1.0f) + cls / denom;
    }
}

extern "C" void kernel_launch(void* const* d_in, const int* in_sizes, int n_in,
                              void* d_out, int out_size, void* d_ws, size_t ws_size,
                              hipStream_t stream) {
    const float* pred = (const float*)d_in[0];
    const float* targ = (const float*)d_in[1];
    float* part = (float*)d_ws;
    float* out = (float*)d_out;

    const int ncells = in_sizes[0] / D_DIM;   // B * S * S

    yolo_fused_kernel<<<SB, 256, 0, stream>>>(pred, targ, part, ncells);
    yolo_final_kernel<<<1, 1024, 0, stream>>>(part, out, pred, targ, SB, ncells);
}

// Round 7
// 150.796 us; speedup vs baseline: 1.0957x; 1.0601x over previous
//
#include <hip/hip_runtime.h>

#define GRID_S 7
#define NUM_CLASSES 80
#define D_DIM 90
#define LAMBDA_COORD 5.0f
#define LAMBDA_NOOBJ 0.5f
#define EPS_IOU 1e-6f
#define EPS_SQRT 1e-6f

__device__ __forceinline__ float iou_img(float cx1, float cy1, float w1, float h1,
                                         float cx2, float cy2, float w2, float h2) {
    float ixmin = fmaxf(cx1 - w1 * 0.5f, cx2 - w2 * 0.5f);
    float iymin = fmaxf(cy1 - h1 * 0.5f, cy2 - h2 * 0.5f);
    float ixmax = fminf(cx1 + w1 * 0.5f, cx2 + w2 * 0.5f);
    float iymax = fminf(cy1 + h1 * 0.5f, cy2 + h2 * 0.5f);
    float iw = fmaxf(ixmax - ixmin, 0.0f);
    float ih = fmaxf(iymax - iymin, 0.0f);
    float inter = iw * ih;
    float uni = w1 * h1 + w2 * h2 - inter;
    return inter / (uni + EPS_IOU);
}

// part layout: per block, 4 floats: [n_obj, coord, conf, cls]
// Obj-gated: class data (80/90 of all bytes) is only read for obj cells (~25%).
__global__ __launch_bounds__(256) void yolo_gated_kernel(
        const float* __restrict__ pred, const float* __restrict__ targ,
        float* __restrict__ part, int ncells) {
    const int tid = threadIdx.x;
    const int cell = blockIdx.x * 256 + tid;

    __shared__ int s_list[256];
    __shared__ int s_count;
    if (tid == 0) s_count = 0;
    __syncthreads();

    float v_obj = 0.0f, v_coord = 0.0f, v_conf = 0.0f, v_cls = 0.0f;

    // ---- phase 1: flag + noobj-conf (3 float2 loads per cell) ----
    bool obj = false;
    if (cell < ncells) {
        const float2* t2 = (const float2*)(targ + (size_t)cell * D_DIM);
        const float2* p2 = (const float2*)(pred + (size_t)cell * D_DIM);
        float2 tf = t2[2];   // targ[4] (obj flag), targ[5]
        float2 pa = p2[2];   // pred[4] (b1 conf), pred[5]
        float2 pb = p2[4];   // pred[8], pred[9] (b2 conf)
        obj = (tf.x == 1.0f);
        if (obj) {
            v_obj = 1.0f;
        } else {
            v_conf = LAMBDA_NOOBJ * (pa.x * pa.x + pb.y * pb.y);
        }
    }

    // ---- compact obj cells into LDS list ----
    if (obj) {
        int idx = atomicAdd(&s_count, 1);
        s_list[idx] = cell;
    }
    __syncthreads();
    const int n = s_count;

    // ---- phase 2: full loss for obj cells; entries 0..n-1 -> threads 0..n-1,
    //      so the expensive gather loop runs with fully-active lanes ----
    for (int k = tid; k < n; k += 256) {
        const int c = s_list[k];
        const float2* p2 = (const float2*)(pred + (size_t)c * D_DIM);
        const float2* t2 = (const float2*)(targ + (size_t)c * D_DIM);

        float2 pq0 = p2[0], pq1 = p2[1], pq2 = p2[2], pq3 = p2[3], pq4 = p2[4];
        float2 tq0 = t2[0], tq1 = t2[1];

        // class sum: float2 idx 5..44 of both arrays (8B-aligned), full unroll for MLP
        float cls0 = 0.0f, cls1 = 0.0f;
        #pragma unroll
        for (int j = 5; j < 45; ++j) {
            float2 pc = p2[j];
            float2 tc = t2[j];
            float dx = pc.x - tc.x;
            float dy = pc.y - tc.y;
            cls0 = fmaf(dx, dx, cls0);
            cls1 = fmaf(dy, dy, cls1);
        }

        float b1x = pq0.x, b1y = pq0.y, b1w = pq1.x, b1h = pq1.y, b1c = pq2.x;
        float b2x = pq2.y, b2y = pq3.x, b2w = pq3.y, b2h = pq4.x, b2c = pq4.y;
        float tbx = tq0.x, tby = tq0.y, tbw = tq1.x, tbh = tq1.y;

        const int gxy = c % (GRID_S * GRID_S);
        const float gy = (float)(gxy / GRID_S);
        const float gx = (float)(gxy % GRID_S);
        const float invS = 1.0f / (float)GRID_S;
        float c1x = (gx + b1x) * invS, c1y = (gy + b1y) * invS;
        float c2x = (gx + b2x) * invS, c2y = (gy + b2y) * invS;
        float ctx = (gx + tbx) * invS, cty = (gy + tby) * invS;

        float iou1 = iou_img(c1x, c1y, b1w, b1h, ctx, cty, tbw, tbh);
        float iou2 = iou_img(c2x, c2y, b2w, b2h, ctx, cty, tbw, tbh);
        bool resp1 = iou1 > iou2;

        float bx = resp1 ? b1x : b2x;
        float by = resp1 ? b1y : b2y;
        float bw = resp1 ? b1w : b2w;
        float bh = resp1 ? b1h : b2h;
        float bc = resp1 ? b1c : b2c;

        float ddx = bx - tbx, ddy = by - tby;
        float dxy2 = ddx * ddx + ddy * ddy;
        float swpw = sqrtf(fmaxf(bw, EPS_SQRT));
        float swph = sqrtf(fmaxf(bh, EPS_SQRT));
        float swtw = sqrtf(fmaxf(tbw, EPS_SQRT));
        float swth = sqrtf(fmaxf(tbh, EPS_SQRT));
        float dw = swpw - swtw, dh = swph - swth;
        float dwh2 = dw * dw + dh * dh;

        v_coord += 0.5f * dxy2 + 0.5f * dwh2;
        float dco = bc - 1.0f;
        v_conf += dco * dco;
        v_cls += (cls0 + cls1) * (1.0f / (float)NUM_CLASSES);
    }

    // ---- block reduction ----
    #pragma unroll
    for (int off = 32; off > 0; off >>= 1) {
        v_obj   += __shfl_down(v_obj, off, 64);
        v_coord += __shfl_down(v_coord, off, 64);
        v_conf  += __shfl_down(v_conf, off, 64);
        v_cls   += __shfl_down(v_cls, off, 64);
    }
    __shared__ float red[4][4];
    const int lane = tid & 63;
    const int wid = tid >> 6;
    if (lane == 0) {
        red[wid][0] = v_obj;
        red[wid][1] = v_coord;
        red[wid][2] = v_conf;
        red[wid][3] = v_cls;
    }
    __syncthreads();
    if (tid < 4) {
        float s = red[0][tid] + red[1][tid] + red[2][tid] + red[3][tid];
        part[(size_t)blockIdx.x * 4 + tid] = s;
    }
}

__global__ __launch_bounds__(1024) void yolo_final_kernel(
        const float* __restrict__ part, float* __restrict__ out,
        int nblocks, int ncells) {
    const int tid = threadIdx.x;
    float a0 = 0.0f, a1 = 0.0f, a2 = 0.0f, a3 = 0.0f;
    const float4* p4 = (const float4*)part;
    for (int b = tid; b < nblocks; b += 1024) {
        float4 v = p4[b];
        a0 += v.x; a1 += v.y; a2 += v.z; a3 += v.w;
    }
    #pragma unroll
    for (int off = 32; off > 0; off >>= 1) {
        a0 += __shfl_down(a0, off, 64);
        a1 += __shfl_down(a1, off, 64);
        a2 += __shfl_down(a2, off, 64);
        a3 += __shfl_down(a3, off, 64);
    }
    __shared__ float red[16][4];
    const int wid = tid >> 6;
    if ((tid & 63) == 0) {
        red[wid][0] = a0; red[wid][1] = a1; red[wid][2] = a2; red[wid][3] = a3;
    }
    __syncthreads();
    if (tid == 0) {
        float n_obj = 0.0f, coord = 0.0f, conf = 0.0f, cls = 0.0f;
        #pragma unroll
        for (int w = 0; w < 16; ++w) {
            n_obj += red[w][0]; coord += red[w][1];
            conf  += red[w][2]; cls   += red[w][3];
        }
        float n_cells = (float)ncells;
        float conf_count = n_obj + 2.0f * (n_cells - n_obj);
        float denom = fmaxf(n_obj, 1.0f);
        out[0] = LAMBDA_COORD * coord / denom + conf / fmaxf(conf_count, 1.0f) + cls / denom;
    }
}

extern "C" void kernel_launch(void* const* d_in, const int* in_sizes, int n_in,
                              void* d_out, int out_size, void* d_ws, size_t ws_size,
                              hipStream_t stream) {
    const float* pred = (const float*)d_in[0];
    const float* targ = (const float*)d_in[1];
    float* part = (float*)d_ws;
    float* out = (float*)d_out;

    const int ncells = in_sizes[0] / D_DIM;      // B * S * S
    const int nblocks = (ncells + 255) / 256;    // 784 for the bench shape

    yolo_gated_kernel<<<nblocks, 256, 0, stream>>>(pred, targ, part, ncells);
    yolo_final_kernel<<<1, 1024, 0, stream>>>(part, out, nblocks, ncells);
}